// Round 18
// baseline (117.318 us; speedup 1.0000x reference)
//
#include <hip/hip_runtime.h>

// MoP fused kernel for MI355X (gfx950).
// B=65536, OBS=256, GOAL=64, S=16, H=128, A=32.
// d_out = [mixed (B*32 f32)] ++ [alphas (B*16 f32)]
// R18: R12 at 4 waves x 64 rows (nb=4), launch_bounds(256,1).
// Halves per-CU LDS W1-read redundancy (8->4 waves each reading 64KB/skill)
// while keeping total MFMA work constant. t-outer chains (R12) make
// 1 wave/SIMD viable (in-wave ILP); LDS biases keep prologue off critical
// path. R4 tested this shape with ht-outer+global biases and failed - those
// defects are fixed here.

typedef __attribute__((ext_vector_type(8))) short    bf16x8;  // 8 bf16, 4 VGPR
typedef __attribute__((ext_vector_type(4))) float    f32x4;
typedef __attribute__((ext_vector_type(4))) _Float16 f16x4;
using half2v = decltype(__builtin_amdgcn_cvt_pkrtz(0.f, 0.f));  // __fp16 x2

// ---- gate image (XOR-swizzled W, one-time use) ----
#define GATE_W1_OFF   0        // Wa1^T bf16: 128 rows x 640 B = 81920
#define GATE_W2_OFF   81920    // Wa2^T f16: 16 rows x 256 B = 4096
#define GATE_BA1_OFF  86016    // ba1 f32[128] = 512
#define GATE_BA2_OFF  86528    // ba2 f32[16]  = 64
#define GATE_BYTES    86592
// ---- skill images (pad-based, immediate-offset reads) ----
#define S_W1_STRIDE   528      // 128 rows -> 67584 B
#define S_W2_OFF      67584    // 32 rows x 272 B = 8704
#define S_W2_STRIDE   272
#define S_B1_OFF      76288    // b1 f32[128] = 512
#define S_B2_OFF      76800    // b2 f32[32]  = 128
#define S_IMG         76928
#define LDS_BYTES     163520   // bufA [0,86592) gate/odd skills, bufB [86592,+76928)

__device__ __forceinline__ unsigned short f2bf(float f) {
  unsigned u = __builtin_bit_cast(unsigned, f);
  return (unsigned short)((u + 0x7FFFu + ((u >> 16) & 1u)) >> 16);  // RNE
}

__device__ __forceinline__ bf16x8 pack_bf8(f32x4 a, f32x4 b) {
  int4 r;
  asm("v_cvt_pk_bf16_f32 %0, %1, %2" : "=v"(r.x) : "v"(a[0]), "v"(a[1]));
  asm("v_cvt_pk_bf16_f32 %0, %1, %2" : "=v"(r.y) : "v"(a[2]), "v"(a[3]));
  asm("v_cvt_pk_bf16_f32 %0, %1, %2" : "=v"(r.z) : "v"(b[0]), "v"(b[1]));
  asm("v_cvt_pk_bf16_f32 %0, %1, %2" : "=v"(r.w) : "v"(b[2]), "v"(b[3]));
  return __builtin_bit_cast(bf16x8, r);
}

#define RELU_SCALE_PACK(dst, v, av, z)                                   \
  {                                                                      \
    half2v lo_ = __builtin_amdgcn_cvt_pkrtz((v)[0], (v)[1]);             \
    half2v hi_ = __builtin_amdgcn_cvt_pkrtz((v)[2], (v)[3]);             \
    lo_ = __builtin_elementwise_max(lo_, z) * (av);                      \
    hi_ = __builtin_elementwise_max(hi_, z) * (av);                      \
    dst[0] = (_Float16)lo_[0]; dst[1] = (_Float16)lo_[1];                \
    dst[2] = (_Float16)hi_[0]; dst[3] = (_Float16)hi_[1];                \
  }

// ---------------- weight prep: f32 -> bf16/f16 LDS images in ws -------------
__global__ void prep_weights(const float* __restrict__ Wa1, const float* __restrict__ Wa2,
                             const float* __restrict__ ba1, const float* __restrict__ ba2,
                             const float* __restrict__ W1,  const float* __restrict__ W2,
                             const float* __restrict__ b1,  const float* __restrict__ b2,
                             unsigned char* __restrict__ ws) {
  int i = blockIdx.x * 256 + threadIdx.x;
  if (i < 524288) {                       // W1 [16][256][128] -> bf16 W1^T rows (h)
    int s = i >> 15, r = i & 32767, h = r >> 8, o = r & 255;
    float v = W1[(s * 256 + o) * 128 + h];
    *(unsigned short*)(ws + GATE_BYTES + s * S_IMG + h * S_W1_STRIDE + 2 * o) = f2bf(v);
  } else if (i < 589824) {                // W2 [16][128][32] -> f16 W2^T rows (a)
    int j = i - 524288, s = j >> 12, r = j & 4095, a = r >> 7, h = r & 127;
    float v = W2[(s * 128 + h) * 32 + a];
    *(_Float16*)(ws + GATE_BYTES + s * S_IMG + S_W2_OFF + a * S_W2_STRIDE + 2 * h) =
        (_Float16)v;
  } else if (i < 630784) {                // Wa1 [320][128] -> bf16 Wa1^T rows, XOR swz
    int j = i - 589824, h = j / 320, o = j - h * 320;
    float v = Wa1[o * 128 + h];
    *(unsigned short*)(ws + GATE_W1_OFF + h * 640 +
                       ((2 * o) ^ ((h & 7) << 4))) = f2bf(v);
  } else if (i < 632832) {                // Wa2 [128][16] -> f16 Wa2^T rows, XOR swz
    int j = i - 630784, n = j >> 7, h = j & 127;
    float v = Wa2[h * 16 + n];
    *(_Float16*)(ws + GATE_W2_OFF + n * 256 +
                 ((2 * h) ^ ((n & 7) << 3))) = (_Float16)v;
  } else if (i < 634880) {                // b1 [16][128] f32
    int j = i - 632832, s = j >> 7, h = j & 127;
    *(float*)(ws + GATE_BYTES + s * S_IMG + S_B1_OFF + 4 * h) = b1[s * 128 + h];
  } else if (i < 635392) {                // b2 [16][32] f32
    int j = i - 634880, s = j >> 5, a = j & 31;
    *(float*)(ws + GATE_BYTES + s * S_IMG + S_B2_OFF + 4 * a) = b2[s * 32 + a];
  } else if (i < 635520) {                // ba1 [128] f32
    int j = i - 635392;
    *(float*)(ws + GATE_BA1_OFF + 4 * j) = ba1[j];
  } else if (i < 635536) {                // ba2 [16] f32
    int j = i - 635520;
    *(float*)(ws + GATE_BA2_OFF + 4 * j) = ba2[j];
  }
}

__device__ __forceinline__ void stage_lin(const unsigned char* gsrc, unsigned char* ldst,
                                          int tid, int bytes) {
  for (int off = tid * 16; off < bytes; off += 256 * 16) {
    __builtin_amdgcn_global_load_lds(
        (const __attribute__((address_space(1))) unsigned int*)(const void*)(gsrc + off),
        (__attribute__((address_space(3))) unsigned int*)(void*)(ldst + off), 16, 0, 0);
  }
}

// ------------------------------- fused main ---------------------------------
// 256 blocks x 256 threads (4 waves, 1/SIMD), 1 block/CU, 256 batch rows/block,
// 64 rows per wave (nb=4). launch_bounds(256,1) -> 512-reg cap, ~310 live.
__global__ __launch_bounds__(256, 1)
void mop_fused(const float* __restrict__ obs, const float* __restrict__ goals,
               const unsigned char* __restrict__ ws, float* __restrict__ dout) {
  extern __shared__ unsigned char smem[];
  const int tid  = threadIdx.x;
  const int lane = tid & 63;
  const int wave = tid >> 6;          // 0..3
  const int l15  = lane & 15;
  const int g    = lane >> 4;
  const int swz4 = (lane & 7) << 4;   // gate W1 swizzle (row&7 == l15&7)
  const int swz3 = (lane & 7) << 3;   // gate W2 swizzle
  const int rowbase = blockIdx.x * 256 + wave * 64;

  float* out_mixed = dout;
  float* out_alpha = dout + 65536 * 32;

  // per-lane skill-image base offsets (within an image)
  const int lw1 = l15 * S_W1_STRIDE + 16 * g;           // + ht*8448 + t*64 (imm)
  const int lw2 = S_W2_OFF + l15 * S_W2_STRIDE + 8 * g; // + ta*4352 + ht*32 (imm)
  const int lb  = 16 * g;                               // bias broadcast base

  // stage gate image into bufA (skill0 staged after barrier, overlaps gate compute)
  stage_lin(ws, smem, tid, GATE_BYTES);

  // obs/goals B-fragments in registers (B-frag: n = l15, k = 8g+j contiguous)
  bf16x8 obsf[4][8];
  bf16x8 goalf[4][2];
  #pragma unroll
  for (int nb = 0; nb < 4; ++nb) {
    const float* rp = obs + (size_t)(rowbase + nb * 16 + l15) * 256 + 8 * g;
    #pragma unroll
    for (int t = 0; t < 8; ++t) {
      f32x4 a = *(const f32x4*)(rp + 32 * t);
      f32x4 c = *(const f32x4*)(rp + 32 * t + 4);
      obsf[nb][t] = pack_bf8(a, c);
    }
    const float* gp = goals + (size_t)(rowbase + nb * 16 + l15) * 64 + 8 * g;
    #pragma unroll
    for (int t = 0; t < 2; ++t) {
      f32x4 a = *(const f32x4*)(gp + 32 * t);
      f32x4 c = *(const f32x4*)(gp + 32 * t + 4);
      goalf[nb][t] = pack_bf8(a, c);
    }
  }

  __syncthreads();   // gate image resident

  // skill0 staging in flight during gate compute; post-gate barrier drains it
  stage_lin(ws + GATE_BYTES, smem + GATE_BYTES, tid, S_IMG);

  // ---- gate layer 1: ha^T = Wa1^T x concat^T  (K = 320, 10 ksteps) ----
  f32x4 gacc[4][8];
  #pragma unroll
  for (int ht = 0; ht < 8; ++ht) {
    f32x4 bias = *(const f32x4*)(smem + GATE_BA1_OFF + 64 * ht + lb);
    #pragma unroll
    for (int nb = 0; nb < 4; ++nb) gacc[nb][ht] = bias;
  }
  #pragma unroll
  for (int t = 0; t < 10; ++t) {
    bf16x8 bf[4];
    #pragma unroll
    for (int nb = 0; nb < 4; ++nb) bf[nb] = (t < 8) ? obsf[nb][t] : goalf[nb][t - 8];
    #pragma unroll
    for (int ht = 0; ht < 8; ++ht) {
      int row = 16 * ht + l15;
      bf16x8 af = *(const bf16x8*)(smem + GATE_W1_OFF + row * 640 +
                                   ((64 * t + 16 * g) ^ swz4));
      #pragma unroll
      for (int nb = 0; nb < 4; ++nb)
        gacc[nb][ht] = __builtin_amdgcn_mfma_f32_16x16x32_bf16(af, bf[nb], gacc[nb][ht], 0, 0, 0);
    }
  }

  // ---- gate layer 2 + softmax; C-layout feeds mfma16 B-frag directly ----
  const half2v zh = __builtin_amdgcn_cvt_pkrtz(0.f, 0.f);
  f32x4 alph[4];
  #pragma unroll
  for (int nb = 0; nb < 4; ++nb) {
    f32x4 lacc = *(const f32x4*)(smem + GATE_BA2_OFF + lb);
    #pragma unroll
    for (int ht = 0; ht < 8; ++ht) {
      f32x4 v = gacc[nb][ht];
      f16x4 hf;
      {
        half2v lo_ = __builtin_amdgcn_cvt_pkrtz(v[0], v[1]);
        half2v hi_ = __builtin_amdgcn_cvt_pkrtz(v[2], v[3]);
        lo_ = __builtin_elementwise_max(lo_, zh);
        hi_ = __builtin_elementwise_max(hi_, zh);
        hf[0] = (_Float16)lo_[0]; hf[1] = (_Float16)lo_[1];
        hf[2] = (_Float16)hi_[0]; hf[3] = (_Float16)hi_[1];
      }
      f16x4 wf = *(const f16x4*)(smem + GATE_W2_OFF + l15 * 256 +
                                 ((32 * ht + 8 * g) ^ swz3));
      lacc = __builtin_amdgcn_mfma_f32_16x16x16f16(wf, hf, lacc, 0, 0, 0);
    }
    // softmax over 16 logits: 4 regs here x lanes {l, l^16, l^32, l^48}
    float m = fmaxf(fmaxf(lacc[0], lacc[1]), fmaxf(lacc[2], lacc[3]));
    m = fmaxf(m, __shfl_xor(m, 16, 64));
    m = fmaxf(m, __shfl_xor(m, 32, 64));
    f32x4 e;
    e[0] = __expf(lacc[0] - m); e[1] = __expf(lacc[1] - m);
    e[2] = __expf(lacc[2] - m); e[3] = __expf(lacc[3] - m);
    float ssum = e[0] + e[1] + e[2] + e[3];
    ssum += __shfl_xor(ssum, 16, 64);
    ssum += __shfl_xor(ssum, 32, 64);
    float inv = 1.0f / ssum;
    alph[nb] = e * inv;
    *(f32x4*)(out_alpha + (size_t)(rowbase + nb * 16 + l15) * 16 + 4 * g) = alph[nb];
  }

  __syncthreads();   // skill0 resident; all waves done with gate LDS region

  // ---- skill loop: t-outer, 32 independent chains, dbuf staging ----
  f32x4 macc[4][2] = {};
  for (int s = 0; s < 16; ++s) {
    const unsigned char* buf = smem + ((s & 1) ? 0 : GATE_BYTES);
    if (s < 15) {
      unsigned char* nbuf = smem + (((s + 1) & 1) ? 0 : GATE_BYTES);
      stage_lin(ws + GATE_BYTES + (size_t)(s + 1) * S_IMG, nbuf, tid, S_IMG);
    }
    // biases from the staged image (broadcast ds_read)
    f32x4 acc[4][8];
    #pragma unroll
    for (int ht = 0; ht < 8; ++ht) {
      f32x4 b1v = *(const f32x4*)(buf + S_B1_OFF + 64 * ht + lb);
      #pragma unroll
      for (int nb = 0; nb < 4; ++nb) acc[nb][ht] = b1v;
    }

    // alpha[s][batch=l15] via component-select + shfl from the holding lane
    const int asrc = ((s >> 2) << 4) | l15;
    float av[4];
    half2v ah[4];
    #pragma unroll
    for (int nb = 0; nb < 4; ++nb) {
      float c0 = (s & 1) ? alph[nb][1] : alph[nb][0];
      float c1 = (s & 1) ? alph[nb][3] : alph[nb][2];
      av[nb] = __shfl((s & 2) ? c1 : c0, asrc, 64);
      ah[nb] = __builtin_amdgcn_cvt_pkrtz(av[nb], av[nb]);
    }

    const unsigned char* w1p = buf + lw1;
    const unsigned char* w2p = buf + lw2;

    __builtin_amdgcn_s_setprio(1);
    // ---- layer 1: t outer, 32 independent accumulator chains ----
    #pragma unroll
    for (int t = 0; t < 8; ++t) {
      const unsigned char* w1t = w1p + t * 64;
      #pragma unroll
      for (int ht = 0; ht < 8; ++ht) {
        bf16x8 af = *(const bf16x8*)(w1t + ht * 8448);   // imm offsets
        #pragma unroll
        for (int nb = 0; nb < 4; ++nb)
          acc[nb][ht] = __builtin_amdgcn_mfma_f32_16x16x32_bf16(af, obsf[nb][t], acc[nb][ht], 0, 0, 0);
      }
    }
    // ---- epilogue: relu+alpha pack, layer 2 ----
    #pragma unroll
    for (int ht = 0; ht < 8; ++ht) {
      f16x4 hf[4];
      #pragma unroll
      for (int nb = 0; nb < 4; ++nb) RELU_SCALE_PACK(hf[nb], acc[nb][ht], ah[nb], zh);
      #pragma unroll
      for (int ta = 0; ta < 2; ++ta) {
        f16x4 wf = *(const f16x4*)(w2p + ta * 4352 + ht * 32);   // imm offsets
        #pragma unroll
        for (int nb = 0; nb < 4; ++nb)
          macc[nb][ta] = __builtin_amdgcn_mfma_f32_16x16x16f16(wf, hf[nb], macc[nb][ta], 0, 0, 0);
      }
    }
    __builtin_amdgcn_s_setprio(0);
    // + alpha_s * b2[s]  (zeros in this test, kept for generality)
    #pragma unroll
    for (int ta = 0; ta < 2; ++ta) {
      f32x4 b2v = *(const f32x4*)(buf + S_B2_OFF + 64 * ta + lb);
      #pragma unroll
      for (int nb = 0; nb < 4; ++nb)
        macc[nb][ta] = macc[nb][ta] + b2v * av[nb];
    }
    __syncthreads();   // drains next-skill stage (vmcnt) + releases buf
  }

  // ---- store mixed: C-layout -> row (a) = 4g+r contiguous => float4 stores ----
  #pragma unroll
  for (int nb = 0; nb < 4; ++nb) {
    #pragma unroll
    for (int ta = 0; ta < 2; ++ta) {
      *(f32x4*)(out_mixed + (size_t)(rowbase + nb * 16 + l15) * 32 + 16 * ta + 4 * g) =
          macc[nb][ta];
    }
  }
}

extern "C" void kernel_launch(void* const* d_in, const int* in_sizes, int n_in,
                              void* d_out, int out_size, void* d_ws, size_t ws_size,
                              hipStream_t stream) {
  const float* obs   = (const float*)d_in[0];
  const float* goals = (const float*)d_in[1];
  const float* Wa1   = (const float*)d_in[2];
  const float* ba1   = (const float*)d_in[3];
  const float* Wa2   = (const float*)d_in[4];
  const float* ba2   = (const float*)d_in[5];
  const float* W1    = (const float*)d_in[6];
  const float* b1    = (const float*)d_in[7];
  const float* W2    = (const float*)d_in[8];
  const float* b2    = (const float*)d_in[9];
  unsigned char* ws  = (unsigned char*)d_ws;
  float* out = (float*)d_out;

  prep_weights<<<2483, 256, 0, stream>>>(Wa1, Wa2, ba1, ba2, W1, W2, b1, b2, ws);
  // 256 blocks x 256 threads (4 waves), 1 block/CU, 256 batch rows/block
  mop_fused<<<256, 256, LDS_BYTES, stream>>>(obs, goals, ws, out);
}

// Round 19
// 93.883 us; speedup vs baseline: 1.2496x; 1.2496x over previous
//
#include <hip/hip_runtime.h>

// MoP fused kernel for MI355X (gfx950).
// B=65536, OBS=256, GOAL=64, S=16, H=128, A=32.
// d_out = [mixed (B*32 f32)] ++ [alphas (B*16 f32)]
// R19 = R12 restored (best known: 93.5us). 8 waves (2/SIMD), nb=2, t-outer
// skill loop with 16 independent MFMA chains, padded conflict-managed LDS
// images with immediate-offset reads, biases staged with weights, dbuf
// staging via global_load_lds, one barrier per skill.
// Plateau note: 6 falsified bottleneck theories (R13-R18) — LDS BW, bank
// conflicts, MFMA count, epilogue overlap, barrier lockstep, occupancy in
// both directions — all returned flat/worse with clean counters. This is
// the structure's ceiling, analogous to the m97-structure ceiling.

typedef __attribute__((ext_vector_type(8))) short    bf16x8;  // 8 bf16, 4 VGPR
typedef __attribute__((ext_vector_type(4))) float    f32x4;
typedef __attribute__((ext_vector_type(4))) _Float16 f16x4;
using half2v = decltype(__builtin_amdgcn_cvt_pkrtz(0.f, 0.f));  // __fp16 x2

// ---- gate image (XOR-swizzled W, one-time use) ----
#define GATE_W1_OFF   0        // Wa1^T bf16: 128 rows x 640 B = 81920
#define GATE_W2_OFF   81920    // Wa2^T f16: 16 rows x 256 B = 4096
#define GATE_BA1_OFF  86016    // ba1 f32[128] = 512
#define GATE_BA2_OFF  86528    // ba2 f32[16]  = 64
#define GATE_BYTES    86592
// ---- skill images (pad-based, immediate-offset reads) ----
#define S_W1_STRIDE   528      // 128 rows -> 67584 B
#define S_W2_OFF      67584    // 32 rows x 272 B = 8704
#define S_W2_STRIDE   272
#define S_B1_OFF      76288    // b1 f32[128] = 512
#define S_B2_OFF      76800    // b2 f32[32]  = 128
#define S_IMG         76928
#define LDS_BYTES     163520   // bufA [0,86592) gate/odd skills, bufB [86592,+76928) even

__device__ __forceinline__ unsigned short f2bf(float f) {
  unsigned u = __builtin_bit_cast(unsigned, f);
  return (unsigned short)((u + 0x7FFFu + ((u >> 16) & 1u)) >> 16);  // RNE
}

__device__ __forceinline__ bf16x8 pack_bf8(f32x4 a, f32x4 b) {
  int4 r;
  asm("v_cvt_pk_bf16_f32 %0, %1, %2" : "=v"(r.x) : "v"(a[0]), "v"(a[1]));
  asm("v_cvt_pk_bf16_f32 %0, %1, %2" : "=v"(r.y) : "v"(a[2]), "v"(a[3]));
  asm("v_cvt_pk_bf16_f32 %0, %1, %2" : "=v"(r.z) : "v"(b[0]), "v"(b[1]));
  asm("v_cvt_pk_bf16_f32 %0, %1, %2" : "=v"(r.w) : "v"(b[2]), "v"(b[3]));
  return __builtin_bit_cast(bf16x8, r);
}

#define RELU_SCALE_PACK(dst, v, av, z)                                   \
  {                                                                      \
    half2v lo_ = __builtin_amdgcn_cvt_pkrtz((v)[0], (v)[1]);             \
    half2v hi_ = __builtin_amdgcn_cvt_pkrtz((v)[2], (v)[3]);             \
    lo_ = __builtin_elementwise_max(lo_, z) * (av);                      \
    hi_ = __builtin_elementwise_max(hi_, z) * (av);                      \
    dst[0] = (_Float16)lo_[0]; dst[1] = (_Float16)lo_[1];                \
    dst[2] = (_Float16)hi_[0]; dst[3] = (_Float16)hi_[1];                \
  }

// ---------------- weight prep: f32 -> bf16/f16 LDS images in ws -------------
__global__ void prep_weights(const float* __restrict__ Wa1, const float* __restrict__ Wa2,
                             const float* __restrict__ ba1, const float* __restrict__ ba2,
                             const float* __restrict__ W1,  const float* __restrict__ W2,
                             const float* __restrict__ b1,  const float* __restrict__ b2,
                             unsigned char* __restrict__ ws) {
  int i = blockIdx.x * 256 + threadIdx.x;
  if (i < 524288) {                       // W1 [16][256][128] -> bf16 W1^T rows (h)
    int s = i >> 15, r = i & 32767, h = r >> 8, o = r & 255;
    float v = W1[(s * 256 + o) * 128 + h];
    *(unsigned short*)(ws + GATE_BYTES + s * S_IMG + h * S_W1_STRIDE + 2 * o) = f2bf(v);
  } else if (i < 589824) {                // W2 [16][128][32] -> f16 W2^T rows (a)
    int j = i - 524288, s = j >> 12, r = j & 4095, a = r >> 7, h = r & 127;
    float v = W2[(s * 128 + h) * 32 + a];
    *(_Float16*)(ws + GATE_BYTES + s * S_IMG + S_W2_OFF + a * S_W2_STRIDE + 2 * h) =
        (_Float16)v;
  } else if (i < 630784) {                // Wa1 [320][128] -> bf16 Wa1^T rows, XOR swz
    int j = i - 589824, h = j / 320, o = j - h * 320;
    float v = Wa1[o * 128 + h];
    *(unsigned short*)(ws + GATE_W1_OFF + h * 640 +
                       ((2 * o) ^ ((h & 7) << 4))) = f2bf(v);
  } else if (i < 632832) {                // Wa2 [128][16] -> f16 Wa2^T rows, XOR swz
    int j = i - 630784, n = j >> 7, h = j & 127;
    float v = Wa2[h * 16 + n];
    *(_Float16*)(ws + GATE_W2_OFF + n * 256 +
                 ((2 * h) ^ ((n & 7) << 3))) = (_Float16)v;
  } else if (i < 634880) {                // b1 [16][128] f32
    int j = i - 632832, s = j >> 7, h = j & 127;
    *(float*)(ws + GATE_BYTES + s * S_IMG + S_B1_OFF + 4 * h) = b1[s * 128 + h];
  } else if (i < 635392) {                // b2 [16][32] f32
    int j = i - 634880, s = j >> 5, a = j & 31;
    *(float*)(ws + GATE_BYTES + s * S_IMG + S_B2_OFF + 4 * a) = b2[s * 32 + a];
  } else if (i < 635520) {                // ba1 [128] f32
    int j = i - 635392;
    *(float*)(ws + GATE_BA1_OFF + 4 * j) = ba1[j];
  } else if (i < 635536) {                // ba2 [16] f32
    int j = i - 635520;
    *(float*)(ws + GATE_BA2_OFF + 4 * j) = ba2[j];
  }
}

__device__ __forceinline__ void stage_lin(const unsigned char* gsrc, unsigned char* ldst,
                                          int tid, int bytes) {
  for (int off = tid * 16; off < bytes; off += 512 * 16) {
    __builtin_amdgcn_global_load_lds(
        (const __attribute__((address_space(1))) unsigned int*)(const void*)(gsrc + off),
        (__attribute__((address_space(3))) unsigned int*)(void*)(ldst + off), 16, 0, 0);
  }
}

// ------------------------------- fused main ---------------------------------
// 256 blocks x 512 threads (8 waves, 2/SIMD), 1 block/CU, 256 batch rows/block,
// 32 rows per wave (nb=2).
__global__ __launch_bounds__(512, 2)
void mop_fused(const float* __restrict__ obs, const float* __restrict__ goals,
               const unsigned char* __restrict__ ws, float* __restrict__ dout) {
  extern __shared__ unsigned char smem[];
  const int tid  = threadIdx.x;
  const int lane = tid & 63;
  const int wave = tid >> 6;          // 0..7
  const int l15  = lane & 15;
  const int g    = lane >> 4;
  const int swz4 = (lane & 7) << 4;   // gate W1 swizzle (row&7 == l15&7)
  const int swz3 = (lane & 7) << 3;   // gate W2 swizzle
  const int rowbase = blockIdx.x * 256 + wave * 32;

  float* out_mixed = dout;
  float* out_alpha = dout + 65536 * 32;

  // per-lane skill-image base offsets (within an image)
  const int lw1 = l15 * S_W1_STRIDE + 16 * g;           // + ht*8448 + t*64 (imm)
  const int lw2 = S_W2_OFF + l15 * S_W2_STRIDE + 8 * g; // + ta*4352 + ht*32 (imm)
  const int lb  = 16 * g;                               // bias broadcast base

  // stage gate image into bufA (skill0 staged after barrier, overlaps gate compute)
  stage_lin(ws, smem, tid, GATE_BYTES);

  // obs/goals B-fragments in registers (B-frag: n = l15, k = 8g+j contiguous)
  bf16x8 obsf[2][8];
  bf16x8 goalf[2][2];
  #pragma unroll
  for (int nb = 0; nb < 2; ++nb) {
    const float* rp = obs + (size_t)(rowbase + nb * 16 + l15) * 256 + 8 * g;
    #pragma unroll
    for (int t = 0; t < 8; ++t) {
      f32x4 a = *(const f32x4*)(rp + 32 * t);
      f32x4 c = *(const f32x4*)(rp + 32 * t + 4);
      obsf[nb][t] = pack_bf8(a, c);
    }
    const float* gp = goals + (size_t)(rowbase + nb * 16 + l15) * 64 + 8 * g;
    #pragma unroll
    for (int t = 0; t < 2; ++t) {
      f32x4 a = *(const f32x4*)(gp + 32 * t);
      f32x4 c = *(const f32x4*)(gp + 32 * t + 4);
      goalf[nb][t] = pack_bf8(a, c);
    }
  }

  __syncthreads();   // gate image resident

  // skill0 staging in flight during gate compute; post-gate barrier drains it
  stage_lin(ws + GATE_BYTES, smem + GATE_BYTES, tid, S_IMG);

  // ---- gate layer 1: ha^T = Wa1^T x concat^T  (K = 320, 10 ksteps) ----
  f32x4 gacc[2][8];
  #pragma unroll
  for (int ht = 0; ht < 8; ++ht) {
    f32x4 bias = *(const f32x4*)(smem + GATE_BA1_OFF + 64 * ht + lb);
    gacc[0][ht] = bias; gacc[1][ht] = bias;
  }
  #pragma unroll
  for (int t = 0; t < 10; ++t) {
    bf16x8 bf0 = (t < 8) ? obsf[0][t] : goalf[0][t - 8];
    bf16x8 bf1 = (t < 8) ? obsf[1][t] : goalf[1][t - 8];
    #pragma unroll
    for (int ht = 0; ht < 8; ++ht) {
      int row = 16 * ht + l15;
      bf16x8 af = *(const bf16x8*)(smem + GATE_W1_OFF + row * 640 +
                                   ((64 * t + 16 * g) ^ swz4));
      gacc[0][ht] = __builtin_amdgcn_mfma_f32_16x16x32_bf16(af, bf0, gacc[0][ht], 0, 0, 0);
      gacc[1][ht] = __builtin_amdgcn_mfma_f32_16x16x32_bf16(af, bf1, gacc[1][ht], 0, 0, 0);
    }
  }

  // ---- gate layer 2 + softmax; C-layout feeds mfma16 B-frag directly ----
  const half2v zh = __builtin_amdgcn_cvt_pkrtz(0.f, 0.f);
  f32x4 alph[2];
  #pragma unroll
  for (int nb = 0; nb < 2; ++nb) {
    f32x4 lacc = *(const f32x4*)(smem + GATE_BA2_OFF + lb);
    #pragma unroll
    for (int ht = 0; ht < 8; ++ht) {
      f32x4 v = gacc[nb][ht];
      f16x4 hf;
      {
        half2v lo_ = __builtin_amdgcn_cvt_pkrtz(v[0], v[1]);
        half2v hi_ = __builtin_amdgcn_cvt_pkrtz(v[2], v[3]);
        lo_ = __builtin_elementwise_max(lo_, zh);
        hi_ = __builtin_elementwise_max(hi_, zh);
        hf[0] = (_Float16)lo_[0]; hf[1] = (_Float16)lo_[1];
        hf[2] = (_Float16)hi_[0]; hf[3] = (_Float16)hi_[1];
      }
      f16x4 wf = *(const f16x4*)(smem + GATE_W2_OFF + l15 * 256 +
                                 ((32 * ht + 8 * g) ^ swz3));
      lacc = __builtin_amdgcn_mfma_f32_16x16x16f16(wf, hf, lacc, 0, 0, 0);
    }
    // softmax over 16 logits: 4 regs here x lanes {l, l^16, l^32, l^48}
    float m = fmaxf(fmaxf(lacc[0], lacc[1]), fmaxf(lacc[2], lacc[3]));
    m = fmaxf(m, __shfl_xor(m, 16, 64));
    m = fmaxf(m, __shfl_xor(m, 32, 64));
    f32x4 e;
    e[0] = __expf(lacc[0] - m); e[1] = __expf(lacc[1] - m);
    e[2] = __expf(lacc[2] - m); e[3] = __expf(lacc[3] - m);
    float ssum = e[0] + e[1] + e[2] + e[3];
    ssum += __shfl_xor(ssum, 16, 64);
    ssum += __shfl_xor(ssum, 32, 64);
    float inv = 1.0f / ssum;
    alph[nb] = e * inv;
    *(f32x4*)(out_alpha + (size_t)(rowbase + nb * 16 + l15) * 16 + 4 * g) = alph[nb];
  }

  __syncthreads();   // skill0 resident; all waves done with gate LDS region

  // ---- skill loop: double-buffered staging, alpha folded into h ----
  // t-OUTER / acc[2][8]-inner: 16 independent MFMA chains, spacing 16.
  f32x4 macc[2][2] = {};
  for (int s = 0; s < 16; ++s) {
    const unsigned char* buf = smem + ((s & 1) ? 0 : GATE_BYTES);
    if (s < 15) {
      unsigned char* nbuf = smem + (((s + 1) & 1) ? 0 : GATE_BYTES);
      stage_lin(ws + GATE_BYTES + (size_t)(s + 1) * S_IMG, nbuf, tid, S_IMG);
    }
    // biases from the staged image (broadcast ds_read)
    f32x4 acc[2][8];
    #pragma unroll
    for (int ht = 0; ht < 8; ++ht) {
      f32x4 b1v = *(const f32x4*)(buf + S_B1_OFF + 64 * ht + lb);
      acc[0][ht] = b1v; acc[1][ht] = b1v;
    }

    // alpha[s][batch=l15] via component-select + shfl from the holding lane
    const int asrc = ((s >> 2) << 4) | l15;
    float p0 = (s & 1) ? alph[0][1] : alph[0][0];
    float p1 = (s & 1) ? alph[0][3] : alph[0][2];
    float as0 = __shfl((s & 2) ? p1 : p0, asrc, 64);
    float q0 = (s & 1) ? alph[1][1] : alph[1][0];
    float q1 = (s & 1) ? alph[1][3] : alph[1][2];
    float as1 = __shfl((s & 2) ? q1 : q0, asrc, 64);
    const half2v a0h = __builtin_amdgcn_cvt_pkrtz(as0, as0);
    const half2v a1h = __builtin_amdgcn_cvt_pkrtz(as1, as1);

    const unsigned char* w1p = buf + lw1;
    const unsigned char* w2p = buf + lw2;

    __builtin_amdgcn_s_setprio(1);
    // ---- layer 1: t outer, 16 independent accumulator chains ----
    #pragma unroll
    for (int t = 0; t < 8; ++t) {
      const unsigned char* w1t = w1p + t * 64;
      #pragma unroll
      for (int ht = 0; ht < 8; ++ht) {
        bf16x8 af = *(const bf16x8*)(w1t + ht * 8448);   // imm offsets
        acc[0][ht] = __builtin_amdgcn_mfma_f32_16x16x32_bf16(af, obsf[0][t], acc[0][ht], 0, 0, 0);
        acc[1][ht] = __builtin_amdgcn_mfma_f32_16x16x32_bf16(af, obsf[1][t], acc[1][ht], 0, 0, 0);
      }
    }
    // ---- epilogue: relu+alpha pack, layer 2 ----
    #pragma unroll
    for (int ht = 0; ht < 8; ++ht) {
      f16x4 hf0, hf1;
      RELU_SCALE_PACK(hf0, acc[0][ht], a0h, zh);
      RELU_SCALE_PACK(hf1, acc[1][ht], a1h, zh);
      #pragma unroll
      for (int ta = 0; ta < 2; ++ta) {
        f16x4 wf = *(const f16x4*)(w2p + ta * 4352 + ht * 32);   // imm offsets
        macc[0][ta] = __builtin_amdgcn_mfma_f32_16x16x16f16(wf, hf0, macc[0][ta], 0, 0, 0);
        macc[1][ta] = __builtin_amdgcn_mfma_f32_16x16x16f16(wf, hf1, macc[1][ta], 0, 0, 0);
      }
    }
    __builtin_amdgcn_s_setprio(0);
    // + alpha_s * b2[s]  (zeros in this test, kept for generality)
    #pragma unroll
    for (int ta = 0; ta < 2; ++ta) {
      f32x4 b2v = *(const f32x4*)(buf + S_B2_OFF + 64 * ta + lb);
      macc[0][ta] = macc[0][ta] + b2v * as0;
      macc[1][ta] = macc[1][ta] + b2v * as1;
    }
    __syncthreads();   // drains next-skill stage (vmcnt) + releases buf
  }

  // ---- store mixed: C-layout -> row (a) = 4g+r contiguous => float4 stores ----
  #pragma unroll
  for (int nb = 0; nb < 2; ++nb) {
    #pragma unroll
    for (int ta = 0; ta < 2; ++ta) {
      *(f32x4*)(out_mixed + (size_t)(rowbase + nb * 16 + l15) * 32 + 16 * ta + 4 * g) =
          macc[nb][ta];
    }
  }
}

extern "C" void kernel_launch(void* const* d_in, const int* in_sizes, int n_in,
                              void* d_out, int out_size, void* d_ws, size_t ws_size,
                              hipStream_t stream) {
  const float* obs   = (const float*)d_in[0];
  const float* goals = (const float*)d_in[1];
  const float* Wa1   = (const float*)d_in[2];
  const float* ba1   = (const float*)d_in[3];
  const float* Wa2   = (const float*)d_in[4];
  const float* ba2   = (const float*)d_in[5];
  const float* W1    = (const float*)d_in[6];
  const float* b1    = (const float*)d_in[7];
  const float* W2    = (const float*)d_in[8];
  const float* b2    = (const float*)d_in[9];
  unsigned char* ws  = (unsigned char*)d_ws;
  float* out = (float*)d_out;

  prep_weights<<<2483, 256, 0, stream>>>(Wa1, Wa2, ba1, ba2, W1, W2, b1, b2, ws);
  mop_fused<<<256, 512, LDS_BYTES, stream>>>(obs, goals, ws, out);
}